// Round 1
// baseline (854.100 us; speedup 1.0000x reference)
//
#include <hip/hip_runtime.h>

// NPG model: E=4 ensembles, B=16384, STATE=29, ACT=8, HID=512.
// R3: 2-blocks/CU restructure. Block = 32 batch rows, 256 threads (4 waves),
// LDS 75.8KB -> 2 blocks/CU (two independent barrier domains hide each
// other's stage/barrier stalls). Wave tile 64x64 (acc[4][4]): per k-step
// 4 LDS A-frags + 4 L2 B-frags -> 16 MFMA (256B LDS + 256B L2 per MFMA).
// h1/h2c use XOR swizzle byte^=(row&7)<<4 (conflict-free b128, G4/T2)
// instead of +8 padding. Layer2 staging: every wave writes its 16-col strip
// and MFMAs its own row strip -> no idle-wave phases.

#define E_ 4
#define B_ 16384

typedef float f32x4 __attribute__((ext_vector_type(4)));
typedef __bf16 bf16x8 __attribute__((ext_vector_type(8)));

__device__ __forceinline__ f32x4 mfma16(bf16x8 a, bf16x8 b, f32x4 c) {
  return __builtin_amdgcn_mfma_f32_16x16x32_bf16(a, b, c, 0, 0, 0);
}

// XOR-swizzled LDS pointer: row stride = 1<<rowshift bytes, 16B-slot swizzle.
__device__ __forceinline__ __bf16* swz_ptr(__bf16* base, int row, int col,
                                           int rowshift) {
  int byte = (row << rowshift) + (col << 1);
  byte ^= (row & 7) << 4;
  return (__bf16*)((char*)base + byte);
}

// leg-format position mapping: output slot 13+k <- leg-block ib, component j
__device__ __forceinline__ void fmt_map(int k, int& ib, int& j) {
  if (k < 8) { ib = k >> 1; j = (k & 1) ? 2 : 0; }
  else { int k8 = k - 8; ib = k8 >> 1; j = (k8 & 1) ? 3 : 1; }
}

// ---------------- prep: pack weights into bf16 MFMA-B-fragment order --------
// Packed W (K x N): tiles (nt,kt) of 32x16; element ((nt*KT+kt)*64+lane)*8+j
// holds W[kt*32 + (lane>>4)*8 + j][nt*16 + (lane&15)]
__device__ __forceinline__ void pack_one(int idx, int per_e, int KT, int Kreal,
                                         int Nsrc, int Nval,
                                         const float* __restrict__ src,
                                         const float* __restrict__ sigma,
                                         __bf16* __restrict__ dst)
{
  int e = idx / per_e;
  int rem = idx - e * per_e;
  int g = rem >> 9;            // nt*KT + kt
  int nt = g / KT;
  int kt = g - nt * KT;
  int li = rem & 511;
  int lane = li >> 3, j = li & 7;
  int k = kt * 32 + (lane >> 4) * 8 + j;
  int n = nt * 16 + (lane & 15);
  float v = 0.f;
  if (k < Kreal && n < Nval) {
    v = src[(size_t)e * Kreal * Nsrc + (size_t)k * Nsrc + n];
    if (sigma) v *= 1.f / (sigma[k] + 1e-8f);   // fold input normalization
  }
  dst[idx] = (__bf16)v;
}

__global__ void prep_kernel(const float* __restrict__ wl0, const float* __restrict__ wl1,
                            const float* __restrict__ wl2, const float* __restrict__ wp0,
                            const float* __restrict__ wp1, const float* __restrict__ wp2,
                            const float* __restrict__ bl0, const float* __restrict__ bp0,
                            const float* __restrict__ mu_leg, const float* __restrict__ sigma_leg,
                            const float* __restrict__ mu_pose, const float* __restrict__ sigma_pose,
                            __bf16* __restrict__ WL0p, __bf16* __restrict__ WL1p,
                            __bf16* __restrict__ WL2p, __bf16* __restrict__ WP0p,
                            __bf16* __restrict__ WP1p, __bf16* __restrict__ WP2p,
                            float* __restrict__ bl0f, float* __restrict__ bp0f)
{
  const int S0 = 65536, S1 = 1048576, S2 = 32768;
  const int total = 2 * (S0 + S1 + S2) + 4096;
  for (int idx0 = blockIdx.x * blockDim.x + threadIdx.x; idx0 < total;
       idx0 += gridDim.x * blockDim.x) {
    int x = idx0;
    if (x < S0)              { pack_one(x, 16384, 1, 6, 512, 512, wl0, sigma_leg, WL0p); }
    else if ((x -= S0) < S1) { pack_one(x, 262144, 16, 512, 512, 512, wl1, nullptr, WL1p); }
    else if ((x -= S1) < S2) { pack_one(x, 8192, 16, 512, 8, 8, wl2, nullptr, WL2p); }
    else if ((x -= S2) < S0) { pack_one(x, 16384, 1, 29, 512, 512, wp0, sigma_pose, WP0p); }
    else if ((x -= S0) < S1) { pack_one(x, 262144, 16, 512, 512, 512, wp1, nullptr, WP1p); }
    else if ((x -= S1) < S2) { pack_one(x, 8192, 16, 512, 26, 16, wp2, nullptr, WP2p); }
    else {
      x -= S2;  // bias folds: b0' = b0 - sum_k mu[k]/(sigma[k]+eps) * W0[k,:]
      if (x < 2048) {
        int e = x >> 9, n = x & 511;
        float s = bl0[e * 512 + n];
        #pragma unroll
        for (int k = 0; k < 6; ++k)
          s -= mu_leg[k] / (sigma_leg[k] + 1e-8f) * wl0[(e * 6 + k) * 512 + n];
        bl0f[e * 512 + n] = s;
      } else {
        x -= 2048;
        int e = x >> 9, n = x & 511;
        float s = bp0[e * 512 + n];
        for (int k = 0; k < 29; ++k)
          s -= mu_pose[k] / (sigma_pose[k] + 1e-8f) * wp0[(e * 29 + k) * 512 + n];
        bp0f[e * 512 + n] = s;
      }
    }
  }
}

// ---------------- fused model kernel ----------------------------------------
__global__ __launch_bounds__(256, 2) void fused_kernel(
    const float* __restrict__ state, const float* __restrict__ act,
    const float* __restrict__ bl1, const float* __restrict__ bl2,
    const float* __restrict__ bp1, const float* __restrict__ bp2,
    const float* __restrict__ mu_t_leg, const float* __restrict__ sigma_t_leg,
    const float* __restrict__ mu_t_pose, const float* __restrict__ sigma_t_pose,
    const __bf16* __restrict__ WL0p, const __bf16* __restrict__ WL1p,
    const __bf16* __restrict__ WL2p, const __bf16* __restrict__ WP0p,
    const __bf16* __restrict__ WP1p, const __bf16* __restrict__ WP2p,
    const float* __restrict__ bl0f, const float* __restrict__ bp0f,
    float* __restrict__ out)
{
  __shared__ alignas(16) __bf16 h1[64 * 512];   // 65536 B, XOR-swizzled
  __shared__ alignas(16) __bf16 h2c[64 * 64];   // 8192 B (union: a0 / pored)
  __shared__ float ldiff[32][16];               // 2048 B   -> total 75776 B
  __bf16* a0s = h2c;                            // a0 <= 64*40*2 = 5120 B

  const int tid = threadIdx.x;
  const int wv = tid >> 6;        // wave 0..3
  const int lane = tid & 63;
  const int quad = lane >> 4;
  const int l16 = lane & 15;
  const int b0 = blockIdx.x * 32;

  // legacc lives in registers: thread owns (t = tid>>3, k in {tid&7, 8+(tid&7)})
  const int lt = tid >> 3;
  const int lk = tid & 7;
  float legacc0 = 0.f, legacc1 = 0.f;
  f32x4 posacc = {0.f, 0.f, 0.f, 0.f};

  for (int e = 0; e < E_; ++e) {
    const float* se = state + (size_t)e * B_ * 29;
    const float* ae = act + (size_t)e * B_ * 8;

    // ================= leg MLP: 2 chunks of 64 leg rows (ib pairs) ==========
    for (int h = 0; h < 2; ++h) {
      __syncthreads();   // prior h2c readers done
      // ---- a0 build: 64 rows (ibl*32 + t) x 32 cols (6 real)
      for (int i = tid; i < 64 * 32; i += 256) {
        int r = i >> 5, c = i & 31;
        int ib = h * 2 + (r >> 5);
        int b = b0 + (r & 31);
        const float* sp = se + (size_t)b * 29;
        float v = 0.f;
        if (c == 0) v = sp[13 + 2 * ib];
        else if (c == 1) v = sp[21 + 2 * ib];
        else if (c == 2) v = sp[14 + 2 * ib];
        else if (c == 3) v = sp[22 + 2 * ib];
        else if (c == 4) v = ae[(size_t)b * 8 + 2 * ib];
        else if (c == 5) v = ae[(size_t)b * 8 + 2 * ib + 1];
        a0s[r * 40 + c] = (__bf16)v;
      }
      __syncthreads();

      // ---- layer0: h1(64x512) = relu(A0 @ W0 + b0'); wave owns 8 col-tiles
      {
        const __bf16* W0 = WL0p + (size_t)e * 16384;
        const float* b0v = bl0f + e * 512;
        bf16x8 bfr[8]; float bs[8];
        #pragma unroll
        for (int i = 0; i < 8; ++i) {
          int ct = wv * 8 + i;
          bfr[i] = *(const bf16x8*)(W0 + ((size_t)ct * 64 + lane) * 8);
          bs[i] = b0v[ct * 16 + l16];
        }
        for (int rt = 0; rt < 4; ++rt) {
          bf16x8 afr = *(const bf16x8*)&a0s[(rt * 16 + l16) * 40 + quad * 8];
          #pragma unroll
          for (int i = 0; i < 8; ++i) {
            f32x4 acc = {bs[i], bs[i], bs[i], bs[i]};
            acc = mfma16(afr, bfr[i], acc);
            int col = (wv * 8 + i) * 16 + l16;
            #pragma unroll
            for (int r = 0; r < 4; ++r)
              *swz_ptr(h1, rt * 16 + quad * 4 + r, col, 10) =
                  (__bf16)fmaxf(acc[r], 0.f);
          }
        }
      }
      __syncthreads();

      // ---- layer1 (64x512x512) + fused layer2; wave tile 64r x 64c
      const __bf16* W1 = WL1p + (size_t)e * 262144;
      const __bf16* W2 = WL2p + (size_t)e * 8192;
      const float* b1v = bl1 + e * 512;
      float bv2 = (l16 < 8) ? bl2[e * 8 + l16] : 0.f;
      f32x4 oacc = {bv2, bv2, bv2, bv2};   // wave wv owns rows wv*16..+15 (l2)

      for (int cc = 0; cc < 2; ++cc) {
        f32x4 acc[4][4];
        #pragma unroll
        for (int ctw = 0; ctw < 4; ++ctw) {
          float bias = b1v[cc * 256 + ctw * 64 + wv * 16 + l16];
          #pragma unroll
          for (int i = 0; i < 4; ++i) acc[i][ctw] = (f32x4){bias, bias, bias, bias};
        }
        #pragma unroll 4
        for (int kt = 0; kt < 16; ++kt) {
          bf16x8 afr[4];
          #pragma unroll
          for (int i = 0; i < 4; ++i)
            afr[i] = *(const bf16x8*)swz_ptr(h1, i * 16 + l16,
                                             kt * 32 + quad * 8, 10);
          #pragma unroll
          for (int ctw = 0; ctw < 4; ++ctw) {
            int nt = cc * 16 + ctw * 4 + wv;
            bf16x8 bfr = *(const bf16x8*)(W1 + (((size_t)nt * 16 + kt) * 64 + lane) * 8);
            #pragma unroll
            for (int i = 0; i < 4; ++i) acc[i][ctw] = mfma16(afr[i], bfr, acc[i][ctw]);
          }
        }
        // stage 64-col strips; every wave writes its 16 cols, MFMAs its rows
        #pragma unroll
        for (int ctw = 0; ctw < 4; ++ctw) {
          __syncthreads();
          #pragma unroll
          for (int i = 0; i < 4; ++i)
            #pragma unroll
            for (int r = 0; r < 4; ++r)
              *swz_ptr(h2c, i * 16 + quad * 4 + r, wv * 16 + l16, 7) =
                  (__bf16)fmaxf(acc[i][ctw][r], 0.f);
          __syncthreads();
          #pragma unroll
          for (int k2 = 0; k2 < 2; ++k2) {
            bf16x8 afr2 = *(const bf16x8*)swz_ptr(h2c, wv * 16 + l16,
                                                  k2 * 32 + quad * 8, 7);
            bf16x8 bfr2 = *(const bf16x8*)(W2 + ((size_t)((cc * 8 + ctw * 2 + k2) * 64 + lane)) * 8);
            oacc = mfma16(afr2, bfr2, oacc);
          }
        }
      }
      // ---- leg epilogue: ldiff (only first 4 outputs used)
      if (l16 < 4) {
        float sc = sigma_t_leg[l16] + 1e-8f;
        float mv = mu_t_leg[l16];
        #pragma unroll
        for (int r = 0; r < 4; ++r) {
          int L = wv * 16 + quad * 4 + r;        // leg row = ibl*32 + t
          int ib = h * 2 + (L >> 5);
          ldiff[L & 31][ib * 4 + l16] = oacc[r] * sc + mv;
        }
      }
    } // h

    // ================= pose MLP: 32 rows =================
    __syncthreads();   // ldiff ready, h2c free
    for (int i = tid; i < 32 * 32; i += 256) {
      int t = i >> 5, c = i & 31;
      float v = 0.f;
      if (c < 13) v = se[(size_t)(b0 + t) * 29 + c];
      else if (c < 29) { int ib, j; fmt_map(c - 13, ib, j); v = ldiff[t][ib * 4 + j]; }
      a0s[t * 40 + c] = (__bf16)v;
    }
    {
      int ib0, j0, ib1, j1;
      fmt_map(lk, ib0, j0); fmt_map(lk + 8, ib1, j1);
      legacc0 += se[(size_t)(b0 + lt) * 29 + 13 + lk] + ldiff[lt][ib0 * 4 + j0];
      legacc1 += se[(size_t)(b0 + lt) * 29 + 21 + lk] + ldiff[lt][ib1 * 4 + j1];
    }
    __syncthreads();

    // ---- pose layer0: h1(32x512)
    {
      const __bf16* W0 = WP0p + (size_t)e * 16384;
      const float* b0v = bp0f + e * 512;
      bf16x8 bfr[8]; float bs[8];
      #pragma unroll
      for (int i = 0; i < 8; ++i) {
        int ct = wv * 8 + i;
        bfr[i] = *(const bf16x8*)(W0 + ((size_t)ct * 64 + lane) * 8);
        bs[i] = b0v[ct * 16 + l16];
      }
      for (int rt = 0; rt < 2; ++rt) {
        bf16x8 afr = *(const bf16x8*)&a0s[(rt * 16 + l16) * 40 + quad * 8];
        #pragma unroll
        for (int i = 0; i < 8; ++i) {
          f32x4 acc = {bs[i], bs[i], bs[i], bs[i]};
          acc = mfma16(afr, bfr[i], acc);
          int col = (wv * 8 + i) * 16 + l16;
          #pragma unroll
          for (int r = 0; r < 4; ++r)
            *swz_ptr(h1, rt * 16 + quad * 4 + r, col, 10) =
                (__bf16)fmaxf(acc[r], 0.f);
        }
      }
    }
    __syncthreads();

    // ---- pose layer1 (32x512x512) + fused layer2 (k-split across wave pairs)
    {
      const __bf16* W1 = WP1p + (size_t)e * 262144;
      const __bf16* W2 = WP2p + (size_t)e * 8192;
      const float* b1v = bp1 + e * 512;
      float bvp = (wv < 2) ? bp2[e * 26 + l16] : 0.f;   // bias once per pair
      f32x4 po = {bvp, bvp, bvp, bvp};

      for (int cc = 0; cc < 2; ++cc) {
        f32x4 acc[2][4];
        #pragma unroll
        for (int ctw = 0; ctw < 4; ++ctw) {
          float bias = b1v[cc * 256 + ctw * 64 + wv * 16 + l16];
          #pragma unroll
          for (int i = 0; i < 2; ++i) acc[i][ctw] = (f32x4){bias, bias, bias, bias};
        }
        #pragma unroll 4
        for (int kt = 0; kt < 16; ++kt) {
          bf16x8 afr[2];
          #pragma unroll
          for (int i = 0; i < 2; ++i)
            afr[i] = *(const bf16x8*)swz_ptr(h1, i * 16 + l16,
                                             kt * 32 + quad * 8, 10);
          #pragma unroll
          for (int ctw = 0; ctw < 4; ++ctw) {
            int nt = cc * 16 + ctw * 4 + wv;
            bf16x8 bfr = *(const bf16x8*)(W1 + (((size_t)nt * 16 + kt) * 64 + lane) * 8);
            #pragma unroll
            for (int i = 0; i < 2; ++i) acc[i][ctw] = mfma16(afr[i], bfr, acc[i][ctw]);
          }
        }
        // stage 128-col strips (ctw pairs); wave (w&1) rows, (w>>1) k-half
        #pragma unroll
        for (int sp = 0; sp < 2; ++sp) {
          __syncthreads();
          #pragma unroll
          for (int cw = 0; cw < 2; ++cw) {
            int ctw = sp * 2 + cw;
            #pragma unroll
            for (int i = 0; i < 2; ++i)
              #pragma unroll
              for (int r = 0; r < 4; ++r)
                *swz_ptr(h2c, i * 16 + quad * 4 + r, cw * 64 + wv * 16 + l16, 8) =
                    (__bf16)fmaxf(acc[i][ctw][r], 0.f);
          }
          __syncthreads();
          #pragma unroll
          for (int kk = 0; kk < 2; ++kk) {
            int k2 = (wv >> 1) * 2 + kk;
            bf16x8 afr2 = *(const bf16x8*)swz_ptr(h2c, (wv & 1) * 16 + l16,
                                                  k2 * 32 + quad * 8, 8);
            int k2g = cc * 8 + sp * 4 + k2;
            bf16x8 bfr2 = *(const bf16x8*)(W2 + ((size_t)(k2g * 64 + lane)) * 8);
            po = mfma16(afr2, bfr2, po);
          }
        }
      }
      // cross-pair k reduction via LDS (waves 2,3 -> waves 0,1)
      __syncthreads();
      float* pored = (float*)h2c;
      if (wv >= 2) {
        #pragma unroll
        for (int r = 0; r < 4; ++r)
          pored[((wv & 1) * 16 + quad * 4 + r) * 16 + l16] = po[r];
      }
      __syncthreads();
      if (wv < 2 && l16 < 13) {
        float sc = sigma_t_pose[l16] + 1e-8f;
        float mv = mu_t_pose[l16];
        #pragma unroll
        for (int r = 0; r < 4; ++r) {
          int row = wv * 16 + quad * 4 + r;
          float tot = po[r] + pored[row * 16 + l16];
          posacc[r] += tot * sc + mv + se[(size_t)(b0 + row) * 29 + l16];
        }
      }
    }
  } // e

  // ================= final writes: mean over ensembles =================
  if (wv < 2 && l16 < 13) {
    #pragma unroll
    for (int r = 0; r < 4; ++r) {
      int row = wv * 16 + quad * 4 + r;
      out[(size_t)(b0 + row) * 29 + l16] = 0.25f * posacc[r];
    }
  }
  out[(size_t)(b0 + lt) * 29 + 13 + lk] = 0.25f * legacc0;
  out[(size_t)(b0 + lt) * 29 + 21 + lk] = 0.25f * legacc1;
}

// ---------------- launch ----------------------------------------------------
extern "C" void kernel_launch(void* const* d_in, const int* in_sizes, int n_in,
                              void* d_out, int out_size, void* d_ws, size_t ws_size,
                              hipStream_t stream) {
  const float* state = (const float*)d_in[0];
  const float* act = (const float*)d_in[1];
  const float* wl0 = (const float*)d_in[2];
  const float* bl0 = (const float*)d_in[3];
  const float* wl1 = (const float*)d_in[4];
  const float* bl1 = (const float*)d_in[5];
  const float* wl2 = (const float*)d_in[6];
  const float* bl2 = (const float*)d_in[7];
  const float* wp0 = (const float*)d_in[8];
  const float* bp0 = (const float*)d_in[9];
  const float* wp1 = (const float*)d_in[10];
  const float* bp1 = (const float*)d_in[11];
  const float* wp2 = (const float*)d_in[12];
  const float* bp2 = (const float*)d_in[13];
  const float* mu_leg = (const float*)d_in[14];
  const float* sigma_leg = (const float*)d_in[15];
  const float* mu_pose = (const float*)d_in[16];
  const float* sigma_pose = (const float*)d_in[17];
  const float* mu_t_leg = (const float*)d_in[18];
  const float* sigma_t_leg = (const float*)d_in[19];
  const float* mu_t_pose = (const float*)d_in[20];
  const float* sigma_t_pose = (const float*)d_in[21];
  float* out = (float*)d_out;

  char* ws = (char*)d_ws;
  __bf16* WL0p = (__bf16*)(ws);
  __bf16* WL1p = (__bf16*)(ws + 131072);
  __bf16* WL2p = (__bf16*)(ws + 2228224);
  __bf16* WP0p = (__bf16*)(ws + 2293760);
  __bf16* WP1p = (__bf16*)(ws + 2424832);
  __bf16* WP2p = (__bf16*)(ws + 4521984);
  float* bl0f = (float*)(ws + 4587520);
  float* bp0f = (float*)(ws + 4595712);

  prep_kernel<<<512, 256, 0, stream>>>(wl0, wl1, wl2, wp0, wp1, wp2, bl0, bp0,
                                       mu_leg, sigma_leg, mu_pose, sigma_pose,
                                       WL0p, WL1p, WL2p, WP0p, WP1p, WP2p,
                                       bl0f, bp0f);
  fused_kernel<<<512, 256, 0, stream>>>(state, act, bl1, bl2, bp1, bp2,
                                        mu_t_leg, sigma_t_leg, mu_t_pose, sigma_t_pose,
                                        WL0p, WL1p, WL2p, WP0p, WP1p, WP2p,
                                        bl0f, bp0f, out);
}